// Round 4
// baseline (131.755 us; speedup 1.0000x reference)
//
#include <hip/hip_runtime.h>
#include <math.h>

#define V_ 3
#define B_ 2
#define C_ 32
#define D_ 32
#define H_ 128
#define W_ 160
#define HW_ (H_*W_)
#define NPIX_ (B_*H_*W_)              // 40960
#define NCOST_ (B_*D_*H_*W_)          // 1310720
#define NFEATT_ (V_*B_*H_*W_*C_)      // 3932160

// ---------------- 4x4 double inverse (adjugate) ----------------
__device__ __forceinline__ void inv4(const double* m, double* o) {
    double inv[16];
    inv[0]  =  m[5]*m[10]*m[15] - m[5]*m[11]*m[14] - m[9]*m[6]*m[15] + m[9]*m[7]*m[14] + m[13]*m[6]*m[11] - m[13]*m[7]*m[10];
    inv[4]  = -m[4]*m[10]*m[15] + m[4]*m[11]*m[14] + m[8]*m[6]*m[15] - m[8]*m[7]*m[14] - m[12]*m[6]*m[11] + m[12]*m[7]*m[10];
    inv[8]  =  m[4]*m[9]*m[15]  - m[4]*m[11]*m[13] - m[8]*m[5]*m[15] + m[8]*m[7]*m[13] + m[12]*m[5]*m[11] - m[12]*m[7]*m[9];
    inv[12] = -m[4]*m[9]*m[14]  + m[4]*m[10]*m[13] + m[8]*m[5]*m[14] - m[8]*m[6]*m[13] - m[12]*m[5]*m[10] + m[12]*m[6]*m[9];
    inv[1]  = -m[1]*m[10]*m[15] + m[1]*m[11]*m[14] + m[9]*m[2]*m[15] - m[9]*m[3]*m[14] - m[13]*m[2]*m[11] + m[13]*m[3]*m[10];
    inv[5]  =  m[0]*m[10]*m[15] - m[0]*m[11]*m[14] - m[8]*m[2]*m[15] + m[8]*m[3]*m[14] + m[12]*m[2]*m[11] - m[12]*m[3]*m[10];
    inv[9]  = -m[0]*m[9]*m[15]  + m[0]*m[11]*m[13] + m[8]*m[1]*m[15] - m[8]*m[3]*m[13] - m[12]*m[1]*m[11] + m[12]*m[3]*m[9];
    inv[13] =  m[0]*m[9]*m[14]  - m[0]*m[10]*m[13] - m[8]*m[1]*m[14] + m[8]*m[2]*m[13] + m[12]*m[1]*m[10] - m[12]*m[2]*m[9];
    inv[2]  =  m[1]*m[6]*m[15]  - m[1]*m[7]*m[14]  - m[5]*m[2]*m[15] + m[5]*m[3]*m[14] + m[13]*m[2]*m[7]  - m[13]*m[3]*m[6];
    inv[6]  = -m[0]*m[6]*m[15]  + m[0]*m[7]*m[14]  + m[4]*m[2]*m[15] - m[4]*m[3]*m[14] - m[12]*m[2]*m[7]  + m[12]*m[3]*m[6];
    inv[10] =  m[0]*m[5]*m[15]  - m[0]*m[7]*m[13]  - m[4]*m[1]*m[15] + m[4]*m[3]*m[13] + m[12]*m[1]*m[7]  - m[12]*m[3]*m[5];
    inv[14] = -m[0]*m[5]*m[14]  + m[0]*m[6]*m[13]  + m[4]*m[1]*m[14] - m[4]*m[2]*m[13] - m[12]*m[1]*m[6]  + m[12]*m[2]*m[5];
    inv[3]  = -m[1]*m[6]*m[11]  + m[1]*m[7]*m[10]  + m[5]*m[2]*m[11] - m[5]*m[3]*m[10] - m[9]*m[2]*m[7]   + m[9]*m[3]*m[6];
    inv[7]  =  m[0]*m[6]*m[11]  - m[0]*m[7]*m[10]  - m[4]*m[2]*m[11] + m[4]*m[3]*m[10] + m[8]*m[2]*m[7]   - m[8]*m[3]*m[6];
    inv[11] = -m[0]*m[5]*m[11]  + m[0]*m[7]*m[9]   + m[4]*m[1]*m[11] - m[4]*m[3]*m[9]  - m[8]*m[1]*m[7]   + m[8]*m[3]*m[5];
    inv[15] =  m[0]*m[5]*m[10]  - m[0]*m[6]*m[9]   - m[4]*m[1]*m[10] + m[4]*m[2]*m[9]  + m[8]*m[1]*m[6]   - m[8]*m[2]*m[5];
    double det = m[0]*inv[0] + m[1]*inv[4] + m[2]*inv[8] + m[3]*inv[12];
    det = 1.0 / det;
    for (int i = 0; i < 16; i++) o[i] = inv[i] * det;
}

__device__ __forceinline__ void mm4(const double* A, const double* Bm, double* Cm) {
    for (int r = 0; r < 4; r++)
        for (int c = 0; c < 4; c++) {
            double s = 0.0;
            for (int k = 0; k < 4; k++) s += A[r*4+k] * Bm[k*4+c];
            Cm[r*4+c] = s;
        }
}

// proj_out: (V-1, B, 12) = rot[9] + trans[3] per (src-view, batch)
__global__ void proj_kernel(const float* __restrict__ K, const float* __restrict__ c2w,
                            float* __restrict__ proj_out) {
    int t = blockIdx.x * blockDim.x + threadIdx.x;
    if (t >= (V_-1) * B_) return;
    int vv = t / B_;
    int b  = t % B_;
    int v  = vv + 1;
    double sc[16], rc[16];
    for (int i = 0; i < 16; i++) {
        sc[i] = (double)c2w[((size_t)v * B_ + b) * 16 + i];
        rc[i] = (double)c2w[((size_t)0 * B_ + b) * 16 + i];
    }
    double sw[16], rw[16];
    inv4(sc, sw);
    inv4(rc, rw);
    double sK[16], rK[16];
    for (int i = 0; i < 16; i++) { sK[i] = sw[i]; rK[i] = rw[i]; }
    for (int r = 0; r < 3; r++)
        for (int c = 0; c < 3; c++) {
            sK[r*4+c] = (double)K[((size_t)v * B_ + b) * 9 + r*3 + c];
            rK[r*4+c] = (double)K[((size_t)0 * B_ + b) * 9 + r*3 + c];
        }
    double sp[16], rp[16], rpi[16], P[16];
    mm4(sK, sw, sp);
    mm4(rK, rw, rp);
    inv4(rp, rpi);
    mm4(sp, rpi, P);
    float* o = proj_out + (size_t)t * 12;
    for (int r = 0; r < 3; r++)
        for (int c = 0; c < 3; c++) o[r*3+c] = (float)P[r*4+c];
    for (int r = 0; r < 3; r++) o[9+r] = (float)P[r*4+3];
}

// features (V,B,C,H,W) -> featT (V,B,H,W,C) via LDS tile (32c x 32x per block)
__global__ void __launch_bounds__(256) transpose_kernel(const float* __restrict__ feat,
                                                        float* __restrict__ featT) {
    __shared__ float lds[32][33];
    int bid = blockIdx.x;
    int xt = bid % (W_ / 32);
    int y  = (bid / (W_ / 32)) % H_;
    int vb = bid / ((W_ / 32) * H_);
    int x0 = xt * 32;
    int tid = threadIdx.x;
    int xl = tid & 31;
    int ch = tid >> 5;   // 0..7
#pragma unroll
    for (int it = 0; it < 4; it++) {
        int c = it * 8 + ch;
        lds[c][xl] = feat[((size_t)(vb * C_ + c) * H_ + y) * W_ + x0 + xl];
    }
    __syncthreads();
    int c4 = tid & 7;
    int xw = tid >> 3;   // 0..31
    float4 o;
    o.x = lds[c4*4+0][xw];
    o.y = lds[c4*4+1][xw];
    o.z = lds[c4*4+2][xw];
    o.w = lds[c4*4+3][xw];
    *(float4*)(featT + ((size_t)(vb * H_ + y) * W_ + x0 + xw) * C_ + c4 * 4) = o;
}

// cost (B,D,H,W): each 8-lane group owns (pixel, 8 consecutive d).
// Block mapping: one d-tile per block, 32 consecutive pixels -> the wave's
// 8 groups gather corners of adjacent pixels at the same depth (line reuse).
__global__ void __launch_bounds__(256, 4) cost_kernel(const float* __restrict__ featT,
                                                      const float* __restrict__ depth,
                                                      const float* __restrict__ unc,
                                                      const float* __restrict__ proj,
                                                      float* __restrict__ cost) {
    int tid = threadIdx.x;
    int g  = tid >> 3;
    int c4 = tid & 7;
    const int blocksPerDt = NPIX_ / 32;           // 1280
    int dt  = blockIdx.x / blocksPerDt;           // 0..3
    int pix = (blockIdx.x % blocksPerDt) * 32 + g;
    int x = pix % W_;
    int y = (pix / W_) % H_;
    int b = pix / (W_ * H_);
    int d0 = dt * 8;

    int idx_d = ((b * D_ + d0 + c4) * H_ + y) * W_ + x;
    float dep = depth[idx_d];

    // per-lane projection for its own d (both views)
    float wgt[2][4];
    int   off[2][4];
    float fx = (float)x, fy = (float)y;
#pragma unroll
    for (int v = 0; v < 2; v++) {
        const float* P = proj + ((size_t)v * B_ + b) * 12;
        float rx = P[0]*fx + P[1]*fy + P[2];
        float ry = P[3]*fx + P[4]*fy + P[5];
        float rz = P[6]*fx + P[7]*fy + P[8];
        float px = rx * dep + P[9];
        float py = ry * dep + P[10];
        float pz = rz * dep + P[11];
        float t0 = px / pz;
        float t1 = py / pz;
        float gx = t0 / ((W_ - 1) * 0.5f) - 1.0f;
        float gy = t1 / ((H_ - 1) * 0.5f) - 1.0f;
        float ix = ((gx + 1.0f) * W_ - 1.0f) * 0.5f;
        float iy = ((gy + 1.0f) * H_ - 1.0f) * 0.5f;
        float x0f = floorf(ix), y0f = floorf(iy);
        float wx = ix - x0f, wy = iy - y0f;
        int x0 = (int)x0f, y0 = (int)y0f;
        int x1 = x0 + 1, y1 = y0 + 1;
        bool vx0 = (x0 >= 0) && (x0 <= W_ - 1);
        bool vx1 = (x1 >= 0) && (x1 <= W_ - 1);
        bool vy0 = (y0 >= 0) && (y0 <= H_ - 1);
        bool vy1 = (y1 >= 0) && (y1 <= H_ - 1);
        wgt[v][0] = (vx0 && vy0) ? (1.0f - wx) * (1.0f - wy) : 0.0f;
        wgt[v][1] = (vx1 && vy0) ? wx * (1.0f - wy) : 0.0f;
        wgt[v][2] = (vx0 && vy1) ? (1.0f - wx) * wy : 0.0f;
        wgt[v][3] = (vx1 && vy1) ? wx * wy : 0.0f;
        int xc0 = min(max(x0, 0), W_ - 1), xc1 = min(max(x1, 0), W_ - 1);
        int yc0 = min(max(y0, 0), H_ - 1), yc1 = min(max(y1, 0), H_ - 1);
        off[v][0] = yc0 * W_ + xc0;
        off[v][1] = yc0 * W_ + xc1;
        off[v][2] = yc1 * W_ + xc0;
        off[v][3] = yc1 * W_ + xc1;
    }

    const float4* fT4 = (const float4*)featT;
    const float4 ref4 = fT4[(size_t)pix * 8 + c4];
    int base1 = (1 * B_ + b) * HW_;   // view 1
    int base2 = (2 * B_ + b) * HW_;   // view 2

    float u = unc[pix];
    float sig = 1.0f / (1.0f + expf(-u));

    float myres = 0.0f;
#pragma unroll
    for (int j = 0; j < 8; j++) {
        float pv[2];
#pragma unroll
        for (int v = 0; v < 2; v++) {
            float W00 = __shfl(wgt[v][0], j, 8);
            float W01 = __shfl(wgt[v][1], j, 8);
            float W10 = __shfl(wgt[v][2], j, 8);
            float W11 = __shfl(wgt[v][3], j, 8);
            int O00 = __shfl(off[v][0], j, 8);
            int O01 = __shfl(off[v][1], j, 8);
            int O10 = __shfl(off[v][2], j, 8);
            int O11 = __shfl(off[v][3], j, 8);
            int base = v ? base2 : base1;
            float4 a  = fT4[(size_t)(base + O00) * 8 + c4];
            float4 bq = fT4[(size_t)(base + O01) * 8 + c4];
            float4 cq = fT4[(size_t)(base + O10) * 8 + c4];
            float4 dq = fT4[(size_t)(base + O11) * 8 + c4];
            float sx = W00*a.x + W01*bq.x + W10*cq.x + W11*dq.x;
            float sy = W00*a.y + W01*bq.y + W10*cq.y + W11*dq.y;
            float sz = W00*a.z + W01*bq.z + W10*cq.z + W11*dq.z;
            float sw = W00*a.w + W01*bq.w + W10*cq.w + W11*dq.w;
            float p = ref4.x*sx + ref4.y*sy + ref4.z*sz + ref4.w*sw;
            p += __shfl_xor(p, 1);
            p += __shfl_xor(p, 2);
            p += __shfl_xor(p, 4);
            pv[v] = p;
        }
        float r = fminf(pv[0], pv[1]) * sig;
        if (c4 == j) myres = r;
    }
    cost[idx_d] = myres;
}

// w_feat: 8 lanes per pixel; softmax over 25 neighbor dots; stored (25, B*H*W)
__global__ void __launch_bounds__(256) wfeat_kernel(const float* __restrict__ featT,
                                                    float* __restrict__ wfeat) {
    int tid = threadIdx.x;
    int g  = tid >> 3;
    int c4 = tid & 7;
    int pix = blockIdx.x * 32 + g;
    int x = pix % W_;
    int y = (pix / W_) % H_;
    int b = pix / (W_ * H_);
    const float4 r = *(const float4*)(featT + (size_t)pix * C_ + c4 * 4);
    float logit[25];
#pragma unroll
    for (int k = 0; k < 25; k++) {
        int dy = k / 5 - 2, dx = k % 5 - 2;
        int ny = y + dy, nx = x + dx;
        float p = 0.0f;
        if (ny >= 0 && ny < H_ && nx >= 0 && nx < W_) {
            const float4 q = *(const float4*)(featT + ((size_t)(b * H_ + ny) * W_ + nx) * C_ + c4 * 4);
            p = r.x*q.x + r.y*q.y + r.z*q.z + r.w*q.w;
        }
        p += __shfl_xor(p, 1);
        p += __shfl_xor(p, 2);
        p += __shfl_xor(p, 4);
        logit[k] = p;
    }
    float m = logit[0];
#pragma unroll
    for (int k = 1; k < 25; k++) m = fmaxf(m, logit[k]);
    float s = 0.0f;
#pragma unroll
    for (int k = 0; k < 25; k++) { logit[k] = expf(logit[k] - m); s += logit[k]; }
    float inv_s = 1.0f / s;
#pragma unroll
    for (int t = 0; t < 3; t++) {
        int k = c4 + 8 * t;
        wfeat[(size_t)k * NPIX_ + pix] = logit[k] * inv_s;
    }
    if (c4 == 0) wfeat[(size_t)24 * NPIX_ + pix] = logit[24] * inv_s;
}

// fused agg + final: block = 8 pixels x 32 d (pixel-major lanes);
// wfeat staged in LDS once per block (was re-read 32x per pixel);
// per-pixel softmax over D done by 8 reducer lanes from LDS.
__global__ void __launch_bounds__(256) aggfinal_kernel(const float* __restrict__ depth,
                                                       const float* __restrict__ cost,
                                                       const float* __restrict__ wfeat,
                                                       float* __restrict__ out) {
    __shared__ float wf[25][8];
    __shared__ float aval[32][8];
    __shared__ float dval[32][8];
    int tid = threadIdx.x;
    int p = tid & 7;
    int d = tid >> 3;
    int pixbase = blockIdx.x * 8;
    int pix = pixbase + p;
    int x = pix % W_;
    int y = (pix / W_) % H_;
    int b = pix / (W_ * H_);

    if (tid < 200) {
        int k = tid >> 3;
        int pp = tid & 7;
        wf[k][pp] = wfeat[(size_t)k * NPIX_ + pixbase + pp];
    }
    __syncthreads();

    int idx = ((b * D_ + d) * H_ + y) * W_ + x;
    float dc = depth[idx];
    size_t dslice = ((size_t)b * D_ + d) * HW_;

    float wd[25];
    float m1 = -1e30f;
#pragma unroll
    for (int k = 0; k < 25; k++) {
        int dy = k / 5 - 2, dx = k % 5 - 2;
        int ny = y + dy, nx = x + dx;
        bool ok = (ny >= 0 && ny < H_ && nx >= 0 && nx < W_);
        float nd = ok ? depth[dslice + ny * W_ + nx] : 0.0f;
        float l = -fabsf(nd - dc);
        wd[k] = l;
        m1 = fmaxf(m1, l);
    }
    float s1 = 0.0f;
#pragma unroll
    for (int k = 0; k < 25; k++) { wd[k] = expf(wd[k] - m1); s1 += wd[k]; }
    float inv_s1 = 1.0f / s1;

    float lg[25];
    float m2 = -1e30f;
#pragma unroll
    for (int k = 0; k < 25; k++) {
        float l = (wd[k] * inv_s1) * wf[k][p];
        lg[k] = l;
        m2 = fmaxf(m2, l);
    }
    float s2 = 0.0f;
    float acc = 0.0f;
#pragma unroll
    for (int k = 0; k < 25; k++) {
        float e = expf(lg[k] - m2);
        s2 += e;
        int dy = k / 5 - 2, dx = k % 5 - 2;
        int ny = y + dy, nx = x + dx;
        bool ok = (ny >= 0 && ny < H_ && nx >= 0 && nx < W_);
        float cv = ok ? cost[dslice + ny * W_ + nx] : 0.0f;
        acc += cv * e;
    }
    aval[d][p] = acc / s2;
    dval[d][p] = dc;
    __syncthreads();

    if (tid < 8) {
        float m = -1e30f;
#pragma unroll
        for (int dd = 0; dd < D_; dd++) m = fmaxf(m, aval[dd][tid]);
        float s = 0.0f, ws = 0.0f;
#pragma unroll
        for (int dd = 0; dd < D_; dd++) {
            float e = expf(aval[dd][tid] - m);
            s += e;
            ws += e * dval[dd][tid];
        }
        out[pixbase + tid] = ws / s;
    }
}

extern "C" void kernel_launch(void* const* d_in, const int* in_sizes, int n_in,
                              void* d_out, int out_size, void* d_ws, size_t ws_size,
                              hipStream_t stream) {
    const float* features = (const float*)d_in[0];  // (3,2,32,128,160)
    const float* intr     = (const float*)d_in[1];  // (3,2,3,3)
    const float* c2w      = (const float*)d_in[2];  // (3,2,4,4)
    const float* depth    = (const float*)d_in[3];  // (2,32,128,160)
    const float* unc      = (const float*)d_in[4];  // (2,128,160)
    float* out = (float*)d_out;

    float* ws    = (float*)d_ws;
    float* featT = ws;                          // NFEATT_
    float* cost  = featT + NFEATT_;             // NCOST_
    float* wfeat = cost + NCOST_;               // 25*NPIX_
    float* proj  = wfeat + (size_t)25 * NPIX_;  // 48

    hipLaunchKernelGGL(proj_kernel, dim3(1), dim3(64), 0, stream, intr, c2w, proj);
    hipLaunchKernelGGL(transpose_kernel, dim3(V_ * B_ * H_ * (W_ / 32)), dim3(256), 0, stream, features, featT);
    hipLaunchKernelGGL(cost_kernel, dim3((NPIX_ * 4) / 32), dim3(256), 0, stream, featT, depth, unc, proj, cost);
    hipLaunchKernelGGL(wfeat_kernel, dim3(NPIX_ / 32), dim3(256), 0, stream, featT, wfeat);
    hipLaunchKernelGGL(aggfinal_kernel, dim3(NPIX_ / 8), dim3(256), 0, stream, depth, cost, wfeat, out);
}

// Round 5
// 113.533 us; speedup vs baseline: 1.1605x; 1.1605x over previous
//
#include <hip/hip_runtime.h>
#include <math.h>

#define V_ 3
#define B_ 2
#define C_ 32
#define D_ 32
#define H_ 128
#define W_ 160
#define HW_ (H_*W_)
#define NPIX_ (B_*H_*W_)              // 40960
#define NCOST_ (B_*D_*H_*W_)          // 1310720
#define NFEATT_ (V_*B_*H_*W_*C_)      // 3932160

// ---------------- 4x4 double inverse (adjugate) ----------------
__device__ __forceinline__ void inv4(const double* m, double* o) {
    double inv[16];
    inv[0]  =  m[5]*m[10]*m[15] - m[5]*m[11]*m[14] - m[9]*m[6]*m[15] + m[9]*m[7]*m[14] + m[13]*m[6]*m[11] - m[13]*m[7]*m[10];
    inv[4]  = -m[4]*m[10]*m[15] + m[4]*m[11]*m[14] + m[8]*m[6]*m[15] - m[8]*m[7]*m[14] - m[12]*m[6]*m[11] + m[12]*m[7]*m[10];
    inv[8]  =  m[4]*m[9]*m[15]  - m[4]*m[11]*m[13] - m[8]*m[5]*m[15] + m[8]*m[7]*m[13] + m[12]*m[5]*m[11] - m[12]*m[7]*m[9];
    inv[12] = -m[4]*m[9]*m[14]  + m[4]*m[10]*m[13] + m[8]*m[5]*m[14] - m[8]*m[6]*m[13] - m[12]*m[5]*m[10] + m[12]*m[6]*m[9];
    inv[1]  = -m[1]*m[10]*m[15] + m[1]*m[11]*m[14] + m[9]*m[2]*m[15] - m[9]*m[3]*m[14] - m[13]*m[2]*m[11] + m[13]*m[3]*m[10];
    inv[5]  =  m[0]*m[10]*m[15] - m[0]*m[11]*m[14] - m[8]*m[2]*m[15] + m[8]*m[3]*m[14] + m[12]*m[2]*m[11] - m[12]*m[3]*m[10];
    inv[9]  = -m[0]*m[9]*m[15]  + m[0]*m[11]*m[13] + m[8]*m[1]*m[15] - m[8]*m[3]*m[13] - m[12]*m[1]*m[11] + m[12]*m[3]*m[9];
    inv[13] =  m[0]*m[9]*m[14]  - m[0]*m[10]*m[13] - m[8]*m[1]*m[14] + m[8]*m[2]*m[13] + m[12]*m[1]*m[10] - m[12]*m[2]*m[9];
    inv[2]  =  m[1]*m[6]*m[15]  - m[1]*m[7]*m[14]  - m[5]*m[2]*m[15] + m[5]*m[3]*m[14] + m[13]*m[2]*m[7]  - m[13]*m[3]*m[6];
    inv[6]  = -m[0]*m[6]*m[15]  + m[0]*m[7]*m[14]  + m[4]*m[2]*m[15] - m[4]*m[3]*m[14] - m[12]*m[2]*m[7]  + m[12]*m[3]*m[6];
    inv[10] =  m[0]*m[5]*m[15]  - m[0]*m[7]*m[13]  - m[4]*m[1]*m[15] + m[4]*m[3]*m[13] + m[12]*m[1]*m[7]  - m[12]*m[3]*m[5];
    inv[14] = -m[0]*m[5]*m[14]  + m[0]*m[6]*m[13]  + m[4]*m[1]*m[14] - m[4]*m[2]*m[13] - m[12]*m[1]*m[6]  + m[12]*m[2]*m[5];
    inv[3]  = -m[1]*m[6]*m[11]  + m[1]*m[7]*m[10]  + m[5]*m[2]*m[11] - m[5]*m[3]*m[10] - m[9]*m[2]*m[7]   + m[9]*m[3]*m[6];
    inv[7]  =  m[0]*m[6]*m[11]  - m[0]*m[7]*m[10]  - m[4]*m[2]*m[11] + m[4]*m[3]*m[10] + m[8]*m[2]*m[7]   - m[8]*m[3]*m[6];
    inv[11] = -m[0]*m[5]*m[11]  + m[0]*m[7]*m[9]   + m[4]*m[1]*m[11] - m[4]*m[3]*m[9]  - m[8]*m[1]*m[7]   + m[8]*m[3]*m[5];
    inv[15] =  m[0]*m[5]*m[10]  - m[0]*m[6]*m[9]   - m[4]*m[1]*m[10] + m[4]*m[2]*m[9]  + m[8]*m[1]*m[6]   - m[8]*m[2]*m[5];
    double det = m[0]*inv[0] + m[1]*inv[4] + m[2]*inv[8] + m[3]*inv[12];
    det = 1.0 / det;
    for (int i = 0; i < 16; i++) o[i] = inv[i] * det;
}

__device__ __forceinline__ void mm4(const double* A, const double* Bm, double* Cm) {
    for (int r = 0; r < 4; r++)
        for (int c = 0; c < 4; c++) {
            double s = 0.0;
            for (int k = 0; k < 4; k++) s += A[r*4+k] * Bm[k*4+c];
            Cm[r*4+c] = s;
        }
}

// proj_out: (V-1, B, 12) = rot[9] + trans[3] per (src-view, batch)
__global__ void proj_kernel(const float* __restrict__ K, const float* __restrict__ c2w,
                            float* __restrict__ proj_out) {
    int t = blockIdx.x * blockDim.x + threadIdx.x;
    if (t >= (V_-1) * B_) return;
    int vv = t / B_;
    int b  = t % B_;
    int v  = vv + 1;
    double sc[16], rc[16];
    for (int i = 0; i < 16; i++) {
        sc[i] = (double)c2w[((size_t)v * B_ + b) * 16 + i];
        rc[i] = (double)c2w[((size_t)0 * B_ + b) * 16 + i];
    }
    double sw[16], rw[16];
    inv4(sc, sw);
    inv4(rc, rw);
    double sK[16], rK[16];
    for (int i = 0; i < 16; i++) { sK[i] = sw[i]; rK[i] = rw[i]; }
    for (int r = 0; r < 3; r++)
        for (int c = 0; c < 3; c++) {
            sK[r*4+c] = (double)K[((size_t)v * B_ + b) * 9 + r*3 + c];
            rK[r*4+c] = (double)K[((size_t)0 * B_ + b) * 9 + r*3 + c];
        }
    double sp[16], rp[16], rpi[16], P[16];
    mm4(sK, sw, sp);
    mm4(rK, rw, rp);
    inv4(rp, rpi);
    mm4(sp, rpi, P);
    float* o = proj_out + (size_t)t * 12;
    for (int r = 0; r < 3; r++)
        for (int c = 0; c < 3; c++) o[r*3+c] = (float)P[r*4+c];
    for (int r = 0; r < 3; r++) o[9+r] = (float)P[r*4+3];
}

// features (V,B,C,H,W) -> featT (V,B,H,W,C) via LDS tile (32c x 32x per block)
__global__ void __launch_bounds__(256) transpose_kernel(const float* __restrict__ feat,
                                                        float* __restrict__ featT) {
    __shared__ float lds[32][33];
    int bid = blockIdx.x;
    int xt = bid % (W_ / 32);
    int y  = (bid / (W_ / 32)) % H_;
    int vb = bid / ((W_ / 32) * H_);
    int x0 = xt * 32;
    int tid = threadIdx.x;
    int xl = tid & 31;
    int ch = tid >> 5;   // 0..7
#pragma unroll
    for (int it = 0; it < 4; it++) {
        int c = it * 8 + ch;
        lds[c][xl] = feat[((size_t)(vb * C_ + c) * H_ + y) * W_ + x0 + xl];
    }
    __syncthreads();
    int c4 = tid & 7;
    int xw = tid >> 3;   // 0..31
    float4 o;
    o.x = lds[c4*4+0][xw];
    o.y = lds[c4*4+1][xw];
    o.z = lds[c4*4+2][xw];
    o.w = lds[c4*4+3][xw];
    *(float4*)(featT + ((size_t)(vb * H_ + y) * W_ + x0 + xw) * C_ + c4 * 4) = o;
}

// cost (B,D,H,W): block = 32 consecutive pixels x 8 depths.
// Phase 1: thread t computes projection for (pixel t&31, depth d0 + t>>5),
//          both views, stores {float4 weights, int4 offsets} to LDS.
// Phase 2: 8-lane group g owns pixel g; loops 8 depths; reads group-uniform
//          projection from LDS (broadcast), gathers channel quarters, blends,
//          dots, butterfly-reduces. Lane c4 keeps result for depth d0+c4.
__global__ void __launch_bounds__(256, 2) cost_kernel(const float* __restrict__ featT,
                                                      const float* __restrict__ depth,
                                                      const float* __restrict__ unc,
                                                      const float* __restrict__ proj,
                                                      float* __restrict__ cost) {
    __shared__ float4 lw[2][256];
    __shared__ int4   lo[2][256];
    int tid = threadIdx.x;
    const int blocksPerDt = NPIX_ / 32;           // 1280
    int dt      = blockIdx.x / blocksPerDt;       // 0..3
    int pixbase = (blockIdx.x % blocksPerDt) * 32;
    int d0 = dt * 8;

    // ---- phase 1: projection per (pixel, d) ----
    {
        int pixl = tid & 31;
        int dl   = tid >> 5;
        int pix = pixbase + pixl;
        int x = pix % W_;
        int y = (pix / W_) % H_;
        int b = pix / (W_ * H_);
        float dep = depth[((b * D_ + d0 + dl) * H_ + y) * W_ + x];
        float fx = (float)x, fy = (float)y;
#pragma unroll
        for (int v = 0; v < 2; v++) {
            const float* P = proj + ((size_t)v * B_ + b) * 12;
            float rx = P[0]*fx + P[1]*fy + P[2];
            float ry = P[3]*fx + P[4]*fy + P[5];
            float rz = P[6]*fx + P[7]*fy + P[8];
            float px = rx * dep + P[9];
            float py = ry * dep + P[10];
            float pz = rz * dep + P[11];
            float inv_pz = 1.0f / pz;
            float t0 = px * inv_pz;
            float t1 = py * inv_pz;
            float gx = t0 / ((W_ - 1) * 0.5f) - 1.0f;
            float gy = t1 / ((H_ - 1) * 0.5f) - 1.0f;
            float ix = ((gx + 1.0f) * W_ - 1.0f) * 0.5f;
            float iy = ((gy + 1.0f) * H_ - 1.0f) * 0.5f;
            float x0f = floorf(ix), y0f = floorf(iy);
            float wx = ix - x0f, wy = iy - y0f;
            int x0 = (int)x0f, y0 = (int)y0f;
            int x1 = x0 + 1, y1 = y0 + 1;
            bool vx0 = (x0 >= 0) && (x0 <= W_ - 1);
            bool vx1 = (x1 >= 0) && (x1 <= W_ - 1);
            bool vy0 = (y0 >= 0) && (y0 <= H_ - 1);
            bool vy1 = (y1 >= 0) && (y1 <= H_ - 1);
            float4 w;
            w.x = (vx0 && vy0) ? (1.0f - wx) * (1.0f - wy) : 0.0f;
            w.y = (vx1 && vy0) ? wx * (1.0f - wy) : 0.0f;
            w.z = (vx0 && vy1) ? (1.0f - wx) * wy : 0.0f;
            w.w = (vx1 && vy1) ? wx * wy : 0.0f;
            int xc0 = min(max(x0, 0), W_ - 1), xc1 = min(max(x1, 0), W_ - 1);
            int yc0 = min(max(y0, 0), H_ - 1), yc1 = min(max(y1, 0), H_ - 1);
            int4 o;
            o.x = yc0 * W_ + xc0;
            o.y = yc0 * W_ + xc1;
            o.z = yc1 * W_ + xc0;
            o.w = yc1 * W_ + xc1;
            lw[v][tid] = w;
            lo[v][tid] = o;
        }
    }
    __syncthreads();

    // ---- phase 2: gather/blend/dot ----
    int g  = tid >> 3;
    int c4 = tid & 7;
    int pix = pixbase + g;
    int x = pix % W_;
    int y = (pix / W_) % H_;
    int b = pix / (W_ * H_);

    const float4* fT4 = (const float4*)featT;
    const float4 ref4 = fT4[(size_t)pix * 8 + c4];
    int base1 = (1 * B_ + b) * HW_;
    int base2 = (2 * B_ + b) * HW_;

    float u = unc[pix];
    float sig = 1.0f / (1.0f + __expf(-u));

    float myres = 0.0f;
#pragma unroll
    for (int dl = 0; dl < 8; dl++) {
        int e = dl * 32 + g;
        float pv[2];
#pragma unroll
        for (int v = 0; v < 2; v++) {
            float4 Wt = lw[v][e];
            int4   Of = lo[v][e];
            int base = v ? base2 : base1;
            float4 a  = fT4[(size_t)(base + Of.x) * 8 + c4];
            float4 bq = fT4[(size_t)(base + Of.y) * 8 + c4];
            float4 cq = fT4[(size_t)(base + Of.z) * 8 + c4];
            float4 dq = fT4[(size_t)(base + Of.w) * 8 + c4];
            float sx = Wt.x*a.x + Wt.y*bq.x + Wt.z*cq.x + Wt.w*dq.x;
            float sy = Wt.x*a.y + Wt.y*bq.y + Wt.z*cq.y + Wt.w*dq.y;
            float sz = Wt.x*a.z + Wt.y*bq.z + Wt.z*cq.z + Wt.w*dq.z;
            float sw = Wt.x*a.w + Wt.y*bq.w + Wt.z*cq.w + Wt.w*dq.w;
            float p = ref4.x*sx + ref4.y*sy + ref4.z*sz + ref4.w*sw;
            p += __shfl_xor(p, 1);
            p += __shfl_xor(p, 2);
            p += __shfl_xor(p, 4);
            pv[v] = p;
        }
        float r = fminf(pv[0], pv[1]) * sig;
        if (c4 == dl) myres = r;
    }
    cost[((b * D_ + d0 + c4) * H_ + y) * W_ + x] = myres;
}

// w_feat: 8 lanes per pixel; softmax over 25 neighbor dots; stored (25, B*H*W)
__global__ void __launch_bounds__(256) wfeat_kernel(const float* __restrict__ featT,
                                                    float* __restrict__ wfeat) {
    int tid = threadIdx.x;
    int g  = tid >> 3;
    int c4 = tid & 7;
    int pix = blockIdx.x * 32 + g;
    int x = pix % W_;
    int y = (pix / W_) % H_;
    int b = pix / (W_ * H_);
    const float4 r = *(const float4*)(featT + (size_t)pix * C_ + c4 * 4);
    float logit[25];
#pragma unroll
    for (int k = 0; k < 25; k++) {
        int dy = k / 5 - 2, dx = k % 5 - 2;
        int ny = y + dy, nx = x + dx;
        float p = 0.0f;
        if (ny >= 0 && ny < H_ && nx >= 0 && nx < W_) {
            const float4 q = *(const float4*)(featT + ((size_t)(b * H_ + ny) * W_ + nx) * C_ + c4 * 4);
            p = r.x*q.x + r.y*q.y + r.z*q.z + r.w*q.w;
        }
        p += __shfl_xor(p, 1);
        p += __shfl_xor(p, 2);
        p += __shfl_xor(p, 4);
        logit[k] = p;
    }
    float m = logit[0];
#pragma unroll
    for (int k = 1; k < 25; k++) m = fmaxf(m, logit[k]);
    float s = 0.0f;
#pragma unroll
    for (int k = 0; k < 25; k++) { logit[k] = __expf(logit[k] - m); s += logit[k]; }
    float inv_s = 1.0f / s;
#pragma unroll
    for (int t = 0; t < 3; t++) {
        int k = c4 + 8 * t;
        wfeat[(size_t)k * NPIX_ + pix] = logit[k] * inv_s;
    }
    if (c4 == 0) wfeat[(size_t)24 * NPIX_ + pix] = logit[24] * inv_s;
}

// fused agg + final: block = 8 pixels x 32 d; depth/cost neighborhoods staged
// in LDS (5 rows x 12 cols x 32 d); wfeat staged once; all exps native.
#define TSTRIDE 61   // 5*12=60 used, 61 to decorrelate banks across d
__global__ void __launch_bounds__(256) aggfinal_kernel(const float* __restrict__ depth,
                                                       const float* __restrict__ cost,
                                                       const float* __restrict__ wfeat,
                                                       float* __restrict__ out) {
    __shared__ float wf[25][8];
    __shared__ float dtile[D_ * TSTRIDE];
    __shared__ float ctile[D_ * TSTRIDE];
    __shared__ float aval[D_][8];
    __shared__ float dval[D_][8];
    int tid = threadIdx.x;
    int p = tid & 7;
    int d = tid >> 3;
    int pixbase = blockIdx.x * 8;
    int x0 = pixbase % W_;
    int yb = (pixbase / W_) % H_;
    int b  = pixbase / (W_ * H_);

    if (tid < 200) {
        int k = tid >> 3;
        int pp = tid & 7;
        wf[k][pp] = wfeat[(size_t)k * NPIX_ + pixbase + pp];
    }
    // stage depth + cost neighborhoods: 32 d x 5 ry x 12 rx
    for (int li = tid; li < D_ * 60; li += 256) {
        int dd = li / 60;
        int rem = li - dd * 60;
        int ry = rem / 12;
        int rx = rem - ry * 12;
        int yy = yb + ry - 2;
        int xx = x0 + rx - 2;
        bool ok = (yy >= 0) && (yy < H_) && (xx >= 0) && (xx < W_);
        size_t gidx = ((size_t)(b * D_ + dd) * H_ + yy) * W_ + xx;
        dtile[dd * TSTRIDE + rem] = ok ? depth[gidx] : 0.0f;
        ctile[dd * TSTRIDE + rem] = ok ? cost[gidx]  : 0.0f;
    }
    __syncthreads();

    const float* dt_ = dtile + d * TSTRIDE;
    const float* ct_ = ctile + d * TSTRIDE;
    float dc = dt_[2 * 12 + p + 2];

    float wd[25];
    float m1 = -1e30f;
#pragma unroll
    for (int k = 0; k < 25; k++) {
        int dy = k / 5, dx = k % 5;
        float nd = dt_[dy * 12 + p + dx];
        float l = -fabsf(nd - dc);
        wd[k] = l;
        m1 = fmaxf(m1, l);
    }
    float s1 = 0.0f;
#pragma unroll
    for (int k = 0; k < 25; k++) { wd[k] = __expf(wd[k] - m1); s1 += wd[k]; }
    float inv_s1 = 1.0f / s1;

    float lg[25];
    float m2 = -1e30f;
#pragma unroll
    for (int k = 0; k < 25; k++) {
        float l = (wd[k] * inv_s1) * wf[k][p];
        lg[k] = l;
        m2 = fmaxf(m2, l);
    }
    float s2 = 0.0f;
    float acc = 0.0f;
#pragma unroll
    for (int k = 0; k < 25; k++) {
        float e = __expf(lg[k] - m2);
        s2 += e;
        int dy = k / 5, dx = k % 5;
        acc += ct_[dy * 12 + p + dx] * e;
    }
    aval[d][p] = acc / s2;
    dval[d][p] = dc;
    __syncthreads();

    if (tid < 8) {
        float m = -1e30f;
#pragma unroll
        for (int dd = 0; dd < D_; dd++) m = fmaxf(m, aval[dd][tid]);
        float s = 0.0f, ws = 0.0f;
#pragma unroll
        for (int dd = 0; dd < D_; dd++) {
            float e = __expf(aval[dd][tid] - m);
            s += e;
            ws += e * dval[dd][tid];
        }
        out[pixbase + tid] = ws / s;
    }
}

extern "C" void kernel_launch(void* const* d_in, const int* in_sizes, int n_in,
                              void* d_out, int out_size, void* d_ws, size_t ws_size,
                              hipStream_t stream) {
    const float* features = (const float*)d_in[0];  // (3,2,32,128,160)
    const float* intr     = (const float*)d_in[1];  // (3,2,3,3)
    const float* c2w      = (const float*)d_in[2];  // (3,2,4,4)
    const float* depth    = (const float*)d_in[3];  // (2,32,128,160)
    const float* unc      = (const float*)d_in[4];  // (2,128,160)
    float* out = (float*)d_out;

    float* ws    = (float*)d_ws;
    float* featT = ws;                          // NFEATT_
    float* cost  = featT + NFEATT_;             // NCOST_
    float* wfeat = cost + NCOST_;               // 25*NPIX_
    float* proj  = wfeat + (size_t)25 * NPIX_;  // 48

    hipLaunchKernelGGL(proj_kernel, dim3(1), dim3(64), 0, stream, intr, c2w, proj);
    hipLaunchKernelGGL(transpose_kernel, dim3(V_ * B_ * H_ * (W_ / 32)), dim3(256), 0, stream, features, featT);
    hipLaunchKernelGGL(cost_kernel, dim3((NPIX_ * 4) / 32), dim3(256), 0, stream, featT, depth, unc, proj, cost);
    hipLaunchKernelGGL(wfeat_kernel, dim3(NPIX_ / 32), dim3(256), 0, stream, featT, wfeat);
    hipLaunchKernelGGL(aggfinal_kernel, dim3(NPIX_ / 8), dim3(256), 0, stream, depth, cost, wfeat, out);
}

// Round 6
// 111.992 us; speedup vs baseline: 1.1765x; 1.0138x over previous
//
#include <hip/hip_runtime.h>
#include <math.h>

#define V_ 3
#define B_ 2
#define C_ 32
#define D_ 32
#define H_ 128
#define W_ 160
#define HW_ (H_*W_)
#define NPIX_ (B_*H_*W_)              // 40960
#define NCOST_ (B_*D_*H_*W_)          // 1310720
#define NFEATT_ (V_*B_*H_*W_*C_)      // 3932160

// ---------------- 4x4 double inverse (adjugate) ----------------
__device__ __forceinline__ void inv4(const double* m, double* o) {
    double inv[16];
    inv[0]  =  m[5]*m[10]*m[15] - m[5]*m[11]*m[14] - m[9]*m[6]*m[15] + m[9]*m[7]*m[14] + m[13]*m[6]*m[11] - m[13]*m[7]*m[10];
    inv[4]  = -m[4]*m[10]*m[15] + m[4]*m[11]*m[14] + m[8]*m[6]*m[15] - m[8]*m[7]*m[14] - m[12]*m[6]*m[11] + m[12]*m[7]*m[10];
    inv[8]  =  m[4]*m[9]*m[15]  - m[4]*m[11]*m[13] - m[8]*m[5]*m[15] + m[8]*m[7]*m[13] + m[12]*m[5]*m[11] - m[12]*m[7]*m[9];
    inv[12] = -m[4]*m[9]*m[14]  + m[4]*m[10]*m[13] + m[8]*m[5]*m[14] - m[8]*m[6]*m[13] - m[12]*m[5]*m[10] + m[12]*m[6]*m[9];
    inv[1]  = -m[1]*m[10]*m[15] + m[1]*m[11]*m[14] + m[9]*m[2]*m[15] - m[9]*m[3]*m[14] - m[13]*m[2]*m[11] + m[13]*m[3]*m[10];
    inv[5]  =  m[0]*m[10]*m[15] - m[0]*m[11]*m[14] - m[8]*m[2]*m[15] + m[8]*m[3]*m[14] + m[12]*m[2]*m[11] - m[12]*m[3]*m[10];
    inv[9]  = -m[0]*m[9]*m[15]  + m[0]*m[11]*m[13] + m[8]*m[1]*m[15] - m[8]*m[3]*m[13] - m[12]*m[1]*m[11] + m[12]*m[3]*m[9];
    inv[13] =  m[0]*m[9]*m[14]  - m[0]*m[10]*m[13] - m[8]*m[1]*m[14] + m[8]*m[2]*m[13] + m[12]*m[1]*m[10] - m[12]*m[2]*m[9];
    inv[2]  =  m[1]*m[6]*m[15]  - m[1]*m[7]*m[14]  - m[5]*m[2]*m[15] + m[5]*m[3]*m[14] + m[13]*m[2]*m[7]  - m[13]*m[3]*m[6];
    inv[6]  = -m[0]*m[6]*m[15]  + m[0]*m[7]*m[14]  + m[4]*m[2]*m[15] - m[4]*m[3]*m[14] - m[12]*m[2]*m[7]  + m[12]*m[3]*m[6];
    inv[10] =  m[0]*m[5]*m[15]  - m[0]*m[7]*m[13]  - m[4]*m[1]*m[15] + m[4]*m[3]*m[13] + m[12]*m[1]*m[7]  - m[12]*m[3]*m[5];
    inv[14] = -m[0]*m[5]*m[14]  + m[0]*m[6]*m[13]  + m[4]*m[1]*m[14] - m[4]*m[2]*m[13] - m[12]*m[1]*m[6]  + m[12]*m[2]*m[5];
    inv[3]  = -m[1]*m[6]*m[11]  + m[1]*m[7]*m[10]  + m[5]*m[2]*m[11] - m[5]*m[3]*m[10] - m[9]*m[2]*m[7]   + m[9]*m[3]*m[6];
    inv[7]  =  m[0]*m[6]*m[11]  - m[0]*m[7]*m[10]  - m[4]*m[2]*m[11] + m[4]*m[3]*m[10] + m[8]*m[2]*m[7]   - m[8]*m[3]*m[6];
    inv[11] = -m[0]*m[5]*m[11]  + m[0]*m[7]*m[9]   + m[4]*m[1]*m[11] - m[4]*m[3]*m[9]  - m[8]*m[1]*m[7]   + m[8]*m[3]*m[5];
    inv[15] =  m[0]*m[5]*m[10]  - m[0]*m[6]*m[9]   - m[4]*m[1]*m[10] + m[4]*m[2]*m[9]  + m[8]*m[1]*m[6]   - m[8]*m[2]*m[5];
    double det = m[0]*inv[0] + m[1]*inv[4] + m[2]*inv[8] + m[3]*inv[12];
    det = 1.0 / det;
    for (int i = 0; i < 16; i++) o[i] = inv[i] * det;
}

__device__ __forceinline__ void mm4(const double* A, const double* Bm, double* Cm) {
    for (int r = 0; r < 4; r++)
        for (int c = 0; c < 4; c++) {
            double s = 0.0;
            for (int k = 0; k < 4; k++) s += A[r*4+k] * Bm[k*4+c];
            Cm[r*4+c] = s;
        }
}

// proj_out: (V-1, B, 12) = rot[9] + trans[3] per (src-view, batch)
__global__ void proj_kernel(const float* __restrict__ K, const float* __restrict__ c2w,
                            float* __restrict__ proj_out) {
    int t = blockIdx.x * blockDim.x + threadIdx.x;
    if (t >= (V_-1) * B_) return;
    int vv = t / B_;
    int b  = t % B_;
    int v  = vv + 1;
    double sc[16], rc[16];
    for (int i = 0; i < 16; i++) {
        sc[i] = (double)c2w[((size_t)v * B_ + b) * 16 + i];
        rc[i] = (double)c2w[((size_t)0 * B_ + b) * 16 + i];
    }
    double sw[16], rw[16];
    inv4(sc, sw);
    inv4(rc, rw);
    double sK[16], rK[16];
    for (int i = 0; i < 16; i++) { sK[i] = sw[i]; rK[i] = rw[i]; }
    for (int r = 0; r < 3; r++)
        for (int c = 0; c < 3; c++) {
            sK[r*4+c] = (double)K[((size_t)v * B_ + b) * 9 + r*3 + c];
            rK[r*4+c] = (double)K[((size_t)0 * B_ + b) * 9 + r*3 + c];
        }
    double sp[16], rp[16], rpi[16], P[16];
    mm4(sK, sw, sp);
    mm4(rK, rw, rp);
    inv4(rp, rpi);
    mm4(sp, rpi, P);
    float* o = proj_out + (size_t)t * 12;
    for (int r = 0; r < 3; r++)
        for (int c = 0; c < 3; c++) o[r*3+c] = (float)P[r*4+c];
    for (int r = 0; r < 3; r++) o[9+r] = (float)P[r*4+3];
}

// features (V,B,C,H,W) -> featT (V,B,H,W,C) via LDS tile (32c x 32x per block)
__global__ void __launch_bounds__(256) transpose_kernel(const float* __restrict__ feat,
                                                        float* __restrict__ featT) {
    __shared__ float lds[32][33];
    int bid = blockIdx.x;
    int xt = bid % (W_ / 32);
    int y  = (bid / (W_ / 32)) % H_;
    int vb = bid / ((W_ / 32) * H_);
    int x0 = xt * 32;
    int tid = threadIdx.x;
    int xl = tid & 31;
    int ch = tid >> 5;   // 0..7
#pragma unroll
    for (int it = 0; it < 4; it++) {
        int c = it * 8 + ch;
        lds[c][xl] = feat[((size_t)(vb * C_ + c) * H_ + y) * W_ + x0 + xl];
    }
    __syncthreads();
    int c4 = tid & 7;
    int xw = tid >> 3;   // 0..31
    float4 o;
    o.x = lds[c4*4+0][xw];
    o.y = lds[c4*4+1][xw];
    o.z = lds[c4*4+2][xw];
    o.w = lds[c4*4+3][xw];
    *(float4*)(featT + ((size_t)(vb * H_ + y) * W_ + x0 + xw) * C_ + c4 * 4) = o;
}

// cost (B,D,H,W): block = 32 consecutive pixels x 8 depths.
// Phase 1: thread t computes projection for (pixel t&31, depth d0 + t>>5).
// Phase 2: 8-lane group owns one pixel, loops 8 depths; all 8 corner gathers
// (both views) are issued up front; next iteration's weights/offsets are
// register-prefetched so LDS reads overlap the blends.
__global__ void __launch_bounds__(256, 4) cost_kernel(const float* __restrict__ featT,
                                                      const float* __restrict__ depth,
                                                      const float* __restrict__ unc,
                                                      const float* __restrict__ proj,
                                                      float* __restrict__ cost) {
    __shared__ float4 lw[2][256];
    __shared__ int4   lo[2][256];
    int tid = threadIdx.x;
    const int blocksPerDt = NPIX_ / 32;           // 1280
    int dt      = blockIdx.x / blocksPerDt;       // 0..3
    int pixbase = (blockIdx.x % blocksPerDt) * 32;
    int d0 = dt * 8;

    // ---- phase 1: projection per (pixel, d) ----
    {
        int pixl = tid & 31;
        int dl   = tid >> 5;
        int pix = pixbase + pixl;
        int x = pix % W_;
        int y = (pix / W_) % H_;
        int b = pix / (W_ * H_);
        float dep = depth[((b * D_ + d0 + dl) * H_ + y) * W_ + x];
        float fx = (float)x, fy = (float)y;
#pragma unroll
        for (int v = 0; v < 2; v++) {
            const float* P = proj + ((size_t)v * B_ + b) * 12;
            float rx = P[0]*fx + P[1]*fy + P[2];
            float ry = P[3]*fx + P[4]*fy + P[5];
            float rz = P[6]*fx + P[7]*fy + P[8];
            float px = rx * dep + P[9];
            float py = ry * dep + P[10];
            float pz = rz * dep + P[11];
            float inv_pz = 1.0f / pz;
            float t0 = px * inv_pz;
            float t1 = py * inv_pz;
            float gx = t0 / ((W_ - 1) * 0.5f) - 1.0f;
            float gy = t1 / ((H_ - 1) * 0.5f) - 1.0f;
            float ix = ((gx + 1.0f) * W_ - 1.0f) * 0.5f;
            float iy = ((gy + 1.0f) * H_ - 1.0f) * 0.5f;
            float x0f = floorf(ix), y0f = floorf(iy);
            float wx = ix - x0f, wy = iy - y0f;
            int x0 = (int)x0f, y0 = (int)y0f;
            int x1 = x0 + 1, y1 = y0 + 1;
            bool vx0 = (x0 >= 0) && (x0 <= W_ - 1);
            bool vx1 = (x1 >= 0) && (x1 <= W_ - 1);
            bool vy0 = (y0 >= 0) && (y0 <= H_ - 1);
            bool vy1 = (y1 >= 0) && (y1 <= H_ - 1);
            float4 w;
            w.x = (vx0 && vy0) ? (1.0f - wx) * (1.0f - wy) : 0.0f;
            w.y = (vx1 && vy0) ? wx * (1.0f - wy) : 0.0f;
            w.z = (vx0 && vy1) ? (1.0f - wx) * wy : 0.0f;
            w.w = (vx1 && vy1) ? wx * wy : 0.0f;
            int xc0 = min(max(x0, 0), W_ - 1), xc1 = min(max(x1, 0), W_ - 1);
            int yc0 = min(max(y0, 0), H_ - 1), yc1 = min(max(y1, 0), H_ - 1);
            int4 o;
            o.x = yc0 * W_ + xc0;
            o.y = yc0 * W_ + xc1;
            o.z = yc1 * W_ + xc0;
            o.w = yc1 * W_ + xc1;
            lw[v][tid] = w;
            lo[v][tid] = o;
        }
    }
    __syncthreads();

    // ---- phase 2 ----
    int g  = tid >> 3;
    int c4 = tid & 7;
    int pix = pixbase + g;
    int x = pix % W_;
    int y = (pix / W_) % H_;
    int b = pix / (W_ * H_);

    const float4* fT4 = (const float4*)featT;
    const float4 ref4 = fT4[(size_t)pix * 8 + c4];
    int base1 = (1 * B_ + b) * HW_;
    int base2 = (2 * B_ + b) * HW_;

    float u = unc[pix];
    float sig = 1.0f / (1.0f + __expf(-u));

    float4 W0 = lw[0][g], W1 = lw[1][g];
    int4   O0 = lo[0][g], O1 = lo[1][g];

    float myres = 0.0f;
#pragma unroll
    for (int dl = 0; dl < 8; dl++) {
        // issue all 8 gathers (both views) up front
        float4 a0 = fT4[(size_t)(base1 + O0.x) * 8 + c4];
        float4 b0 = fT4[(size_t)(base1 + O0.y) * 8 + c4];
        float4 c0 = fT4[(size_t)(base1 + O0.z) * 8 + c4];
        float4 e0 = fT4[(size_t)(base1 + O0.w) * 8 + c4];
        float4 a1 = fT4[(size_t)(base2 + O1.x) * 8 + c4];
        float4 b1 = fT4[(size_t)(base2 + O1.y) * 8 + c4];
        float4 c1 = fT4[(size_t)(base2 + O1.z) * 8 + c4];
        float4 e1 = fT4[(size_t)(base2 + O1.w) * 8 + c4];
        float4 cw0 = W0, cw1 = W1;
        if (dl < 7) {  // register-prefetch next iteration's proj data
            int e = (dl + 1) * 32 + g;
            W0 = lw[0][e]; O0 = lo[0][e];
            W1 = lw[1][e]; O1 = lo[1][e];
        }
        float sx = cw0.x*a0.x + cw0.y*b0.x + cw0.z*c0.x + cw0.w*e0.x;
        float sy = cw0.x*a0.y + cw0.y*b0.y + cw0.z*c0.y + cw0.w*e0.y;
        float sz = cw0.x*a0.z + cw0.y*b0.z + cw0.z*c0.z + cw0.w*e0.z;
        float sw = cw0.x*a0.w + cw0.y*b0.w + cw0.z*c0.w + cw0.w*e0.w;
        float p0 = ref4.x*sx + ref4.y*sy + ref4.z*sz + ref4.w*sw;
        float tx = cw1.x*a1.x + cw1.y*b1.x + cw1.z*c1.x + cw1.w*e1.x;
        float ty = cw1.x*a1.y + cw1.y*b1.y + cw1.z*c1.y + cw1.w*e1.y;
        float tz = cw1.x*a1.z + cw1.y*b1.z + cw1.z*c1.z + cw1.w*e1.z;
        float tw = cw1.x*a1.w + cw1.y*b1.w + cw1.z*c1.w + cw1.w*e1.w;
        float p1 = ref4.x*tx + ref4.y*ty + ref4.z*tz + ref4.w*tw;
        p0 += __shfl_xor(p0, 1);
        p1 += __shfl_xor(p1, 1);
        p0 += __shfl_xor(p0, 2);
        p1 += __shfl_xor(p1, 2);
        p0 += __shfl_xor(p0, 4);
        p1 += __shfl_xor(p1, 4);
        float r = fminf(p0, p1) * sig;
        if (c4 == dl) myres = r;
    }
    cost[((b * D_ + d0 + c4) * H_ + y) * W_ + x] = myres;
}

// w_feat: 8 lanes per pixel; softmax over 25 neighbor dots; stored (25, B*H*W)
__global__ void __launch_bounds__(256) wfeat_kernel(const float* __restrict__ featT,
                                                    float* __restrict__ wfeat) {
    int tid = threadIdx.x;
    int g  = tid >> 3;
    int c4 = tid & 7;
    int pix = blockIdx.x * 32 + g;
    int x = pix % W_;
    int y = (pix / W_) % H_;
    int b = pix / (W_ * H_);
    const float4 r = *(const float4*)(featT + (size_t)pix * C_ + c4 * 4);
    float logit[25];
#pragma unroll
    for (int k = 0; k < 25; k++) {
        int dy = k / 5 - 2, dx = k % 5 - 2;
        int ny = y + dy, nx = x + dx;
        float p = 0.0f;
        if (ny >= 0 && ny < H_ && nx >= 0 && nx < W_) {
            const float4 q = *(const float4*)(featT + ((size_t)(b * H_ + ny) * W_ + nx) * C_ + c4 * 4);
            p = r.x*q.x + r.y*q.y + r.z*q.z + r.w*q.w;
        }
        p += __shfl_xor(p, 1);
        p += __shfl_xor(p, 2);
        p += __shfl_xor(p, 4);
        logit[k] = p;
    }
    float m = logit[0];
#pragma unroll
    for (int k = 1; k < 25; k++) m = fmaxf(m, logit[k]);
    float s = 0.0f;
#pragma unroll
    for (int k = 0; k < 25; k++) { logit[k] = __expf(logit[k] - m); s += logit[k]; }
    float inv_s = 1.0f / s;
#pragma unroll
    for (int t = 0; t < 3; t++) {
        int k = c4 + 8 * t;
        wfeat[(size_t)k * NPIX_ + pix] = logit[k] * inv_s;
    }
    if (c4 == 0) wfeat[(size_t)24 * NPIX_ + pix] = logit[24] * inv_s;
}

// fused agg + final: block = 32 pixels (one x-run) x 32 d.
// depth/cost staged in LDS as [32d][5ry][36rx] (rows 144B-coalesced);
// thread (p = tid&31, dgrp = tid>>5) handles 4 depths for pixel p.
#define AG_DT(arr, dd, ry, rx) arr[((dd) * 5 + (ry)) * 36 + (rx)]
__global__ void __launch_bounds__(256) aggfinal_kernel(const float* __restrict__ depth,
                                                       const float* __restrict__ cost,
                                                       const float* __restrict__ wfeat,
                                                       float* __restrict__ out) {
    __shared__ float dtile[D_ * 5 * 36];
    __shared__ float ctile[D_ * 5 * 36];
    __shared__ float wf[25][32];
    __shared__ float aval[D_][32];
    int tid = threadIdx.x;
    int p    = tid & 31;
    int dgrp = tid >> 5;   // 0..7
    int pixbase = blockIdx.x * 32;
    int x0 = pixbase % W_;
    int yb = (pixbase / W_) % H_;
    int b  = pixbase / (W_ * H_);

    // stage wfeat (25 x 32, coalesced)
    for (int li = tid; li < 25 * 32; li += 256) {
        int k  = li >> 5;
        int pp = li & 31;
        wf[k][pp] = wfeat[(size_t)k * NPIX_ + pixbase + pp];
    }
    // stage depth + cost tiles: 32 d x 5 ry x 36 rx
    for (int li = tid; li < D_ * 5 * 36; li += 256) {
        int dd  = li / 180;
        int rem = li - dd * 180;
        int ry  = rem / 36;
        int rx  = rem - ry * 36;
        int yy = yb + ry - 2;
        int xx = x0 + rx - 2;
        bool ok = (yy >= 0) && (yy < H_) && (xx >= 0) && (xx < W_);
        size_t gidx = ((size_t)(b * D_ + dd) * H_ + yy) * W_ + xx;
        dtile[li] = ok ? depth[gidx] : 0.0f;
        ctile[li] = ok ? cost[gidx]  : 0.0f;
    }
    __syncthreads();

#pragma unroll
    for (int i = 0; i < 4; i++) {
        int d = dgrp * 4 + i;
        float dc = AG_DT(dtile, d, 2, p + 2);

        float wd[25];
        float m1 = -1e30f;
#pragma unroll
        for (int k = 0; k < 25; k++) {
            int dy = k / 5, dx = k % 5;
            float nd = AG_DT(dtile, d, dy, p + dx);
            float l = -fabsf(nd - dc);
            wd[k] = l;
            m1 = fmaxf(m1, l);
        }
        float s1 = 0.0f;
#pragma unroll
        for (int k = 0; k < 25; k++) { wd[k] = __expf(wd[k] - m1); s1 += wd[k]; }
        float inv_s1 = 1.0f / s1;

        float lg[25];
        float m2 = -1e30f;
#pragma unroll
        for (int k = 0; k < 25; k++) {
            float l = (wd[k] * inv_s1) * wf[k][p];
            lg[k] = l;
            m2 = fmaxf(m2, l);
        }
        float s2 = 0.0f;
        float acc = 0.0f;
#pragma unroll
        for (int k = 0; k < 25; k++) {
            float e = __expf(lg[k] - m2);
            s2 += e;
            int dy = k / 5, dx = k % 5;
            acc += AG_DT(ctile, d, dy, p + dx) * e;
        }
        aval[d][p] = acc / s2;
    }
    __syncthreads();

    if (tid < 32) {
        float m = -1e30f;
#pragma unroll
        for (int dd = 0; dd < D_; dd++) m = fmaxf(m, aval[dd][tid]);
        float s = 0.0f, ws = 0.0f;
#pragma unroll
        for (int dd = 0; dd < D_; dd++) {
            float e = __expf(aval[dd][tid] - m);
            s += e;
            ws += e * AG_DT(dtile, dd, 2, tid + 2);
        }
        out[pixbase + tid] = ws / s;
    }
}

extern "C" void kernel_launch(void* const* d_in, const int* in_sizes, int n_in,
                              void* d_out, int out_size, void* d_ws, size_t ws_size,
                              hipStream_t stream) {
    const float* features = (const float*)d_in[0];  // (3,2,32,128,160)
    const float* intr     = (const float*)d_in[1];  // (3,2,3,3)
    const float* c2w      = (const float*)d_in[2];  // (3,2,4,4)
    const float* depth    = (const float*)d_in[3];  // (2,32,128,160)
    const float* unc      = (const float*)d_in[4];  // (2,128,160)
    float* out = (float*)d_out;

    float* ws    = (float*)d_ws;
    float* featT = ws;                          // NFEATT_
    float* cost  = featT + NFEATT_;             // NCOST_
    float* wfeat = cost + NCOST_;               // 25*NPIX_
    float* proj  = wfeat + (size_t)25 * NPIX_;  // 48

    hipLaunchKernelGGL(proj_kernel, dim3(1), dim3(64), 0, stream, intr, c2w, proj);
    hipLaunchKernelGGL(transpose_kernel, dim3(V_ * B_ * H_ * (W_ / 32)), dim3(256), 0, stream, features, featT);
    hipLaunchKernelGGL(cost_kernel, dim3((NPIX_ * 4) / 32), dim3(256), 0, stream, featT, depth, unc, proj, cost);
    hipLaunchKernelGGL(wfeat_kernel, dim3(NPIX_ / 32), dim3(256), 0, stream, featT, wfeat);
    hipLaunchKernelGGL(aggfinal_kernel, dim3(NPIX_ / 32), dim3(256), 0, stream, depth, cost, wfeat, out);
}